// Round 3
// 550.440 us; speedup vs baseline: 1.0105x; 1.0105x over previous
//
#include <hip/hip_runtime.h>
#include <hip/hip_bf16.h>

#define B_ 32
#define S_ 2048
#define D_ 512

typedef __attribute__((ext_vector_type(8))) short bf16x8;   // 8 bf16 = 4 VGPRs
typedef __attribute__((ext_vector_type(4))) float f32x4;    // MFMA 16x16 accumulator
typedef unsigned short ushort_t;

__device__ __forceinline__ float b2f(ushort_t u) {
  union { unsigned int i; float f; } v; v.i = ((unsigned int)u) << 16; return v.f;
}
__device__ __forceinline__ ushort_t f2b(float f) {   // RTNE fp32 -> bf16 bits
  union { float f; unsigned int i; } v; v.f = f;
  return (ushort_t)((v.i + 0x7FFFu + ((v.i >> 16) & 1u)) >> 16);
}

__device__ __forceinline__ f32x4 mfma16(bf16x8 a, bf16x8 b, f32x4 c) {
  return __builtin_amdgcn_mfma_f32_16x16x32_bf16(a, b, c, 0, 0, 0);
}

// ---------------------------------------------------------------------------
// dtype detection: 1 = bf16 storage, 0 = fp32 storage.
// ---------------------------------------------------------------------------
__global__ void detect_kernel(const unsigned int* __restrict__ w, int* __restrict__ flag) {
  __shared__ int cnt;
  if (threadIdx.x == 0) cnt = 0;
  __syncthreads();
  int c = 0;
  #pragma unroll
  for (int i = 0; i < 4; ++i) {
    unsigned int v = w[threadIdx.x + i * 256];
    unsigned int e = (v >> 7) & 0xFFu;
    if (e >= 110u && e <= 140u) ++c;
  }
  atomicAdd(&cnt, c);
  __syncthreads();
  if (threadIdx.x == 0) flag[0] = (cnt > 512) ? 1 : 0;
}

template <int DT>
__device__ __forceinline__ float ldf(const void* p, size_t idx) {
  if constexpr (DT == 0) return ((const float*)p)[idx];
  else                   return b2f(((const ushort_t*)p)[idx]);
}

// read one 8-element (K=32) MFMA fragment from a row-stride-32 swizzled tile.
__device__ __forceinline__ bf16x8 read_frag(const ushort_t* tile, int row, int quad) {
  int g = quad ^ ((row >> 1) & 3);
  return *(const bf16x8*)(tile + row * 32 + g * 8);
}

// ---------------------------------------------------------------------------
// Staging helpers, split into load (issue early) / store (convert+ds_write late)
// so HBM/L2 latency hides under the MFMA phase (T14 async-STAGE split).
// ---------------------------------------------------------------------------

// [128 x 32] tile with 256 threads: thread t = (row t>>1, half t&1), 16 elems.
template <int DT> struct TR16 { float4 f[4]; bf16x8 h[2]; };

template <int DT>
__device__ __forceinline__ void t16_load(const void* gv, size_t base, int tid, TR16<DT>& t) {
  const int row = tid >> 1, half = tid & 1;
  const size_t off = base + (size_t)row * D_ + half * 16;
  if constexpr (DT == 0) {
    const float4* s = (const float4*)((const float*)gv + off);
    t.f[0] = s[0]; t.f[1] = s[1]; t.f[2] = s[2]; t.f[3] = s[3];
  } else {
    const bf16x8* s = (const bf16x8*)((const ushort_t*)gv + off);
    t.h[0] = s[0]; t.h[1] = s[1];
  }
}
template <int DT>
__device__ __forceinline__ void t16_store(ushort_t* tile, int tid, const TR16<DT>& t) {
  const int row = tid >> 1, half = tid & 1;
  bf16x8 ch0, ch1;
  if constexpr (DT == 0) {
    ushort_t u[16];
    u[0]  = f2b(t.f[0].x); u[1]  = f2b(t.f[0].y); u[2]  = f2b(t.f[0].z); u[3]  = f2b(t.f[0].w);
    u[4]  = f2b(t.f[1].x); u[5]  = f2b(t.f[1].y); u[6]  = f2b(t.f[1].z); u[7]  = f2b(t.f[1].w);
    u[8]  = f2b(t.f[2].x); u[9]  = f2b(t.f[2].y); u[10] = f2b(t.f[2].z); u[11] = f2b(t.f[2].w);
    u[12] = f2b(t.f[3].x); u[13] = f2b(t.f[3].y); u[14] = f2b(t.f[3].z); u[15] = f2b(t.f[3].w);
    ch0 = *(const bf16x8*)u; ch1 = *(const bf16x8*)(u + 8);
  } else { ch0 = t.h[0]; ch1 = t.h[1]; }
  const int swz = (row >> 1) & 3, c0 = half * 2;
  *(bf16x8*)(tile + row * 32 + (((c0    ) ^ swz) << 3)) = ch0;
  *(bf16x8*)(tile + row * 32 + (((c0 + 1) ^ swz) << 3)) = ch1;
}

// gate A tile [128 x 32] with 512 threads: thread t = (row t>>2, group t&3), 8 elems.
template <int DT> struct TRA { float4 f[2]; bf16x8 h; };

template <int DT>
__device__ __forceinline__ void ta_load(const void* gv, size_t base, int tid, TRA<DT>& t) {
  const int row = tid >> 2, g = tid & 3;
  const size_t off = base + (size_t)row * D_ + g * 8;
  if constexpr (DT == 0) {
    const float4* s = (const float4*)((const float*)gv + off);
    t.f[0] = s[0]; t.f[1] = s[1];
  } else {
    t.h = *(const bf16x8*)((const ushort_t*)gv + off);
  }
}
template <int DT>
__device__ __forceinline__ void ta_store(ushort_t* tile, int tid, const TRA<DT>& t) {
  const int row = tid >> 2, g = tid & 3;
  bf16x8 ch;
  if constexpr (DT == 0) {
    ushort_t u[8];
    u[0] = f2b(t.f[0].x); u[1] = f2b(t.f[0].y); u[2] = f2b(t.f[0].z); u[3] = f2b(t.f[0].w);
    u[4] = f2b(t.f[1].x); u[5] = f2b(t.f[1].y); u[6] = f2b(t.f[1].z); u[7] = f2b(t.f[1].w);
    ch = *(const bf16x8*)u;
  } else ch = t.h;
  const int swz = (row >> 1) & 3;
  *(bf16x8*)(tile + row * 32 + ((g ^ swz) << 3)) = ch;
}

// gate B tile [512 x 32] with 512 threads: thread t stages row t (32 elems).
template <int DT> struct TRB { float4 f[8]; bf16x8 h[4]; };

template <int DT>
__device__ __forceinline__ void tb_load(const void* gv, size_t base, int tid, TRB<DT>& t) {
  const size_t off = base + (size_t)tid * D_;
  if constexpr (DT == 0) {
    const float4* s = (const float4*)((const float*)gv + off);
    #pragma unroll
    for (int i = 0; i < 8; ++i) t.f[i] = s[i];
  } else {
    const bf16x8* s = (const bf16x8*)((const ushort_t*)gv + off);
    #pragma unroll
    for (int i = 0; i < 4; ++i) t.h[i] = s[i];
  }
}
template <int DT>
__device__ __forceinline__ void tb_store(ushort_t* tile, int tid, const TRB<DT>& t) {
  const int row = tid, swz = (row >> 1) & 3;
  #pragma unroll
  for (int g = 0; g < 4; ++g) {
    bf16x8 ch;
    if constexpr (DT == 0) {
      ushort_t u[8];
      float4 a = t.f[2 * g], b = t.f[2 * g + 1];
      u[0] = f2b(a.x); u[1] = f2b(a.y); u[2] = f2b(a.z); u[3] = f2b(a.w);
      u[4] = f2b(b.x); u[5] = f2b(b.y); u[6] = f2b(b.z); u[7] = f2b(b.w);
      ch = *(const bf16x8*)u;
    } else ch = t.h[g];
    *(bf16x8*)(tile + row * 32 + ((g ^ swz) << 3)) = ch;
  }
}

// ---------------------------------------------------------------------------
// Shared-memory layouts, declared ONCE per __global__ kernel and passed into
// both DT instantiations (declaring them inside the template doubles LDS).
// ---------------------------------------------------------------------------
struct GateSmem {
  alignas(16) ushort_t As[2][128 * 32];   // 16 KB
  alignas(16) ushort_t Bs[2][512 * 32];   // 64 KB
  float b1s[512], w2s[512], logit[128];   // 4.5 KB
};
struct OutSmem {
  alignas(16) ushort_t As[2][128 * 32];   // 16 KB
  alignas(16) ushort_t Ss[2][128 * 32];   // 16 KB
  alignas(16) ushort_t Ls[2][128 * 32];   // 16 KB
};

// ---------------------------------------------------------------------------
// Kernel 1: gate[b,s]. One block = 128 s-rows x ALL 512 e (8 waves, 2x4).
// old_x staged ONCE (was 5x); residual computed from the staged LDS tile.
// Single barrier per k-step, double-buffered LDS, loads prefetched 1 step ahead.
// ---------------------------------------------------------------------------
template <int DT>
__device__ __forceinline__ void gate_body(const void* __restrict__ old_x,
    const int* __restrict__ lang, const void* __restrict__ W1,
    const void* __restrict__ b1, const void* __restrict__ W2,
    const void* __restrict__ b2p, float* __restrict__ gate, GateSmem& sm) {
  // XCD-aware chunked swizzle: 512 wg / 8 XCDs = 64 per chunk ->
  // all 16 s-tiles of a given b (sharing W1[lang[b]]) land on one XCD's L2.
  int bid = blockIdx.y * gridDim.x + blockIdx.x;            // 0..511
  int swz = (bid & 7) * 64 + (bid >> 3);
  const int s0 = (swz & 15) * 128;
  const int b  = swz >> 4;
  const int tid  = threadIdx.x;
  const int wave = tid >> 6, lane = tid & 63, quad = lane >> 4, ln = lane & 15;
  const int m_off = (wave >> 2) * 64;      // 2 wave-rows of 64 s
  const int n_off = (wave & 3) * 128;      // 4 wave-cols of 128 e
  const int lg = lang[b];

  sm.b1s[tid] = ldf<DT>(b1, (size_t)lg * 512 + tid);
  sm.w2s[tid] = ldf<DT>(W2, (size_t)lg * 512 + tid);
  if (tid < 128) sm.logit[tid] = 0.f;

  const size_t Aoff = ((size_t)b * S_ + s0) * D_;
  const size_t Boff = (size_t)lg * D_ * D_;

  f32x4 acc[4][8];
  #pragma unroll
  for (int i = 0; i < 4; ++i)
    #pragma unroll
    for (int j = 0; j < 8; ++j) { f32x4 z = {0.f, 0.f, 0.f, 0.f}; acc[i][j] = z; }

  TRA<DT> ta; TRB<DT> tb;
  // B first (L2/L3-resident W1), A last (HBM-streamed old_x): in-order vmcnt
  // retire means B's convert never waits on A's HBM miss.
  tb_load<DT>(W1, Boff, tid, tb);
  ta_load<DT>(old_x, Aoff, tid, ta);
  tb_store<DT>(sm.Bs[0], tid, tb);
  ta_store<DT>(sm.As[0], tid, ta);
  __syncthreads();

  const int rrow  = tid >> 2, rg = tid & 3;
  const int rslot = (rg ^ ((rrow >> 1) & 3)) << 3;
  float res = 0.f;

  for (int step = 0; step < 16; ++step) {
    const int cur = step & 1;
    if (step < 15) {                       // prefetch next k-step into regs
      tb_load<DT>(W1, Boff + (step + 1) * 32, tid, tb);
      ta_load<DT>(old_x, Aoff + (step + 1) * 32, tid, ta);
    }
    bf16x8 af[4];
    #pragma unroll
    for (int mf = 0; mf < 4; ++mf)
      af[mf] = read_frag(sm.As[cur], m_off + mf * 16 + ln, quad);
    {   // residual partial: sum_k old_x[s,k] * w2[k] from staged tile
      bf16x8 rv = *(const bf16x8*)(sm.As[cur] + rrow * 32 + rslot);
      #pragma unroll
      for (int j = 0; j < 8; ++j)
        res += b2f((ushort_t)rv[j]) * sm.w2s[step * 32 + rg * 8 + j];
    }
    #pragma unroll
    for (int nh = 0; nh < 2; ++nh) {       // split B frags to cap live regs
      bf16x8 bfr[4];
      #pragma unroll
      for (int nf = 0; nf < 4; ++nf)
        bfr[nf] = read_frag(sm.Bs[cur], n_off + (nh * 4 + nf) * 16 + ln, quad);
      #pragma unroll
      for (int mf = 0; mf < 4; ++mf)
        #pragma unroll
        for (int nf = 0; nf < 4; ++nf)
          acc[mf][nh * 4 + nf] = mfma16(af[mf], bfr[nf], acc[mf][nh * 4 + nf]);
    }
    if (step < 15) {                       // write the prefetched tile
      const int nxt = cur ^ 1;
      tb_store<DT>(sm.Bs[nxt], tid, tb);
      ta_store<DT>(sm.As[nxt], tid, ta);
    }
    __syncthreads();                       // ONE barrier per k-step
  }
  atomicAdd(&sm.logit[rrow], res);

  float logacc[16];
  #pragma unroll
  for (int i = 0; i < 16; ++i) logacc[i] = 0.f;
  #pragma unroll
  for (int nf = 0; nf < 8; ++nf) {
    int e = n_off + nf * 16 + ln;
    float b1v = sm.b1s[e], w2v = sm.w2s[e];
    #pragma unroll
    for (int mf = 0; mf < 4; ++mf)
      #pragma unroll
      for (int r = 0; r < 4; ++r) {
        float v = acc[mf][nf][r] + b1v;
        logacc[mf * 4 + r] += fmaxf(v, 0.f) * w2v;
      }
  }
  #pragma unroll
  for (int off = 1; off < 16; off <<= 1)
    #pragma unroll
    for (int i = 0; i < 16; ++i)
      logacc[i] += __shfl_xor(logacc[i], off, 64);
  if (ln == 0) {
    #pragma unroll
    for (int mf = 0; mf < 4; ++mf)
      #pragma unroll
      for (int r = 0; r < 4; ++r)
        atomicAdd(&sm.logit[m_off + mf * 16 + quad * 4 + r], logacc[mf * 4 + r]);
  }
  __syncthreads();
  if (tid < 128) {
    float bb = ldf<DT>(b2p, lg);
    float l = sm.logit[tid] + bb;
    gate[(size_t)b * S_ + s0 + tid] = 1.f / (1.f + expf(-l));
  }
}

__global__ __launch_bounds__(512, 2)
void gate_kernel(const void* __restrict__ old_x, const int* __restrict__ lang,
                 const void* __restrict__ W1, const void* __restrict__ b1,
                 const void* __restrict__ W2, const void* __restrict__ b2,
                 const int* __restrict__ flag, float* __restrict__ gate) {
  __shared__ GateSmem sm;                  // single 84.5 KB instance
  if (flag[0] == 0) gate_body<0>(old_x, lang, W1, b1, W2, b2, gate, sm);
  else              gate_body<1>(old_x, lang, W1, b1, W2, b2, gate, sm);
}

// ---------------------------------------------------------------------------
// Kernel 2: out = (1-g)*x@share_W^T + g*x@langs_W[lang]^T
// Same pipeline: 1 barrier/step, dbuf LDS, reg-prefetch, weights-first order.
// ---------------------------------------------------------------------------
template <int DT>
__device__ __forceinline__ void out_body(const void* __restrict__ x,
    const int* __restrict__ lang, const void* __restrict__ shareW,
    const void* __restrict__ langsW, const float* __restrict__ gate,
    void* __restrict__ out, OutSmem& sm) {
  // XCD-aware chunked swizzle: 2048 wg / 8 = 256 per chunk -> the 4 e-tiles
  // sharing an x s-tile run on the same XCD (x tile L2-reused, not re-fetched).
  int bid = (blockIdx.z * gridDim.y + blockIdx.y) * gridDim.x + blockIdx.x;  // 0..2047
  int swz = (bid & 7) * 256 + (bid >> 3);
  const int e0 = (swz & 3) * 128;
  const int s0 = ((swz >> 2) & 15) * 128;
  const int b  = swz >> 6;
  const int tid  = threadIdx.x;
  const int wave = tid >> 6, lane = tid & 63, quad = lane >> 4, ln = lane & 15;
  const int m_off = (wave >> 1) * 64, n_off = (wave & 1) * 64;
  const int lg = lang[b];

  const size_t Aoff = ((size_t)b * S_ + s0) * D_;
  const size_t Soff = (size_t)e0 * D_;
  const size_t Loff = ((size_t)lg * D_ + e0) * D_;

  f32x4 accS[4][4], accL[4][4];
  #pragma unroll
  for (int i = 0; i < 4; ++i)
    #pragma unroll
    for (int j = 0; j < 4; ++j) {
      f32x4 z = {0.f, 0.f, 0.f, 0.f};
      accS[i][j] = z; accL[i][j] = z;
    }

  TR16<DT> ta, ts, tl;
  t16_load<DT>(shareW, Soff, tid, ts);
  t16_load<DT>(langsW, Loff, tid, tl);
  t16_load<DT>(x,      Aoff, tid, ta);
  t16_store<DT>(sm.Ss[0], tid, ts);
  t16_store<DT>(sm.Ls[0], tid, tl);
  t16_store<DT>(sm.As[0], tid, ta);
  __syncthreads();

  for (int step = 0; step < 16; ++step) {
    const int cur = step & 1;
    if (step < 15) {
      t16_load<DT>(shareW, Soff + (step + 1) * 32, tid, ts);
      t16_load<DT>(langsW, Loff + (step + 1) * 32, tid, tl);
      t16_load<DT>(x,      Aoff + (step + 1) * 32, tid, ta);
    }
    bf16x8 af[4], sf[4], lf[4];
    #pragma unroll
    for (int mf = 0; mf < 4; ++mf)
      af[mf] = read_frag(sm.As[cur], m_off + mf * 16 + ln, quad);
    #pragma unroll
    for (int nf = 0; nf < 4; ++nf) {
      sf[nf] = read_frag(sm.Ss[cur], n_off + nf * 16 + ln, quad);
      lf[nf] = read_frag(sm.Ls[cur], n_off + nf * 16 + ln, quad);
    }
    #pragma unroll
    for (int mf = 0; mf < 4; ++mf)
      #pragma unroll
      for (int nf = 0; nf < 4; ++nf) {
        accS[mf][nf] = mfma16(af[mf], sf[nf], accS[mf][nf]);
        accL[mf][nf] = mfma16(af[mf], lf[nf], accL[mf][nf]);
      }
    if (step < 15) {
      const int nxt = cur ^ 1;
      t16_store<DT>(sm.Ss[nxt], tid, ts);
      t16_store<DT>(sm.Ls[nxt], tid, tl);
      t16_store<DT>(sm.As[nxt], tid, ta);
    }
    __syncthreads();
  }

  // epilogue: blend with gate, non-temporal store (output never re-read;
  // keeps x resident in L3 — working set x+out > 256 MB otherwise thrashes).
  #pragma unroll
  for (int mf = 0; mf < 4; ++mf) {
    int srow = s0 + m_off + mf * 16 + quad * 4;
    float gv[4];
    #pragma unroll
    for (int r = 0; r < 4; ++r) gv[r] = gate[(size_t)b * S_ + srow + r];
    #pragma unroll
    for (int nf = 0; nf < 4; ++nf) {
      int col = e0 + n_off + nf * 16 + ln;
      f32x4 cs = accS[mf][nf], cl = accL[mf][nf];
      #pragma unroll
      for (int r = 0; r < 4; ++r) {
        float v = cs[r] + gv[r] * (cl[r] - cs[r]);
        size_t idx = ((size_t)b * S_ + srow + r) * D_ + col;
        if constexpr (DT == 0)
          __builtin_nontemporal_store(v, (float*)out + idx);
        else
          __builtin_nontemporal_store(f2b(v), (ushort_t*)out + idx);
      }
    }
  }
}

__global__ __launch_bounds__(256, 2)
void out_kernel(const void* __restrict__ x, const int* __restrict__ lang,
                const void* __restrict__ shareW, const void* __restrict__ langsW,
                const float* __restrict__ gate, const int* __restrict__ flag,
                void* __restrict__ out) {
  __shared__ OutSmem sm;                   // single 48 KB instance
  if (flag[0] == 0) out_body<0>(x, lang, shareW, langsW, gate, out, sm);
  else              out_body<1>(x, lang, shareW, langsW, gate, out, sm);
}

extern "C" void kernel_launch(void* const* d_in, const int* in_sizes, int n_in,
                              void* d_out, int out_size, void* d_ws, size_t ws_size,
                              hipStream_t stream) {
  const void* old_x  = d_in[0];
  const void* x      = d_in[1];
  const int*  lang   = (const int*)d_in[2];
  const void* shareW = d_in[3];
  const void* langsW = d_in[4];
  const void* gW1    = d_in[5];
  const void* gb1    = d_in[6];
  const void* gW2    = d_in[7];
  const void* gb2    = d_in[8];

  float* gate = (float*)d_ws;                                   // B*S floats
  int*   flag = (int*)((char*)d_ws + (size_t)B_ * S_ * sizeof(float));

  detect_kernel<<<1, 256, 0, stream>>>((const unsigned int*)old_x, flag);

  dim3 g1(S_ / 128, B_);
  gate_kernel<<<g1, dim3(512), 0, stream>>>(old_x, lang, gW1, gb1, gW2, gb2, flag, gate);

  dim3 g2(D_ / 128, S_ / 128, B_);
  out_kernel<<<g2, dim3(256), 0, stream>>>(x, lang, shareW, langsW, gate, flag, d_out);
}

// Round 4
// 448.358 us; speedup vs baseline: 1.2406x; 1.2277x over previous
//
#include <hip/hip_runtime.h>
#include <hip/hip_bf16.h>

#define B_ 32
#define S_ 2048
#define D_ 512

// ---------------------------------------------------------------------------
// workspace layout (bytes). Total ~8.8 MB.
// ---------------------------------------------------------------------------
#define WS_GATE  0                           // 32*2048*4 = 262144
#define WS_FLAG  262144                      // 16 B (padded)
#define WS_SW    266240                      // shareW tiled: 64 tiles * 8192 B
#define WS_LW    (WS_SW + 64 * 8192)         // langsW tiled: 512 tiles
#define WS_W1    (WS_LW + 512 * 8192)        // gate W1 tiled: 512 tiles
#define WS_B1F   (WS_W1 + 512 * 8192)        // b1 as f32: 8*512*4
#define WS_W2F   (WS_B1F + 16384)            // W2 as f32: 8*512*4
#define WS_B2F   (WS_W2F + 16384)            // b2 as f32: 32 B

typedef __attribute__((ext_vector_type(8))) short bf16x8;   // 8 bf16 = 4 VGPRs
typedef __attribute__((ext_vector_type(4))) float f32x4;    // MFMA 16x16 accumulator
typedef unsigned short ushort_t;

__device__ __forceinline__ float b2f(ushort_t u) {
  union { unsigned int i; float f; } v; v.i = ((unsigned int)u) << 16; return v.f;
}
__device__ __forceinline__ ushort_t f2b(float f) {   // RTNE fp32 -> bf16 bits
  union { float f; unsigned int i; } v; v.f = f;
  return (ushort_t)((v.i + 0x7FFFu + ((v.i >> 16) & 1u)) >> 16);
}

__device__ __forceinline__ f32x4 mfma16(bf16x8 a, bf16x8 b, f32x4 c) {
  return __builtin_amdgcn_mfma_f32_16x16x32_bf16(a, b, c, 0, 0, 0);
}

// global -> LDS direct DMA, 16 B per lane. gptr per-lane, lptr wave-uniform.
__device__ __forceinline__ void gload16(const void* g, void* l) {
  __builtin_amdgcn_global_load_lds(
      (const __attribute__((address_space(1))) unsigned int*)g,
      (__attribute__((address_space(3))) unsigned int*)l, 16, 0, 0);
}

// ---------------------------------------------------------------------------
// dtype detection: 1 = bf16 storage, 0 = fp32 storage.
// ---------------------------------------------------------------------------
__global__ void detect_kernel(const unsigned int* __restrict__ w, int* __restrict__ flag) {
  __shared__ int cnt;
  if (threadIdx.x == 0) cnt = 0;
  __syncthreads();
  int c = 0;
  #pragma unroll
  for (int i = 0; i < 4; ++i) {
    unsigned int v = w[threadIdx.x + i * 256];
    unsigned int e = (v >> 7) & 0xFFu;
    if (e >= 110u && e <= 140u) ++c;
  }
  atomicAdd(&cnt, c);
  __syncthreads();
  if (threadIdx.x == 0) flag[0] = (cnt > 512) ? 1 : 0;
}

// read one 8-element (K=32) MFMA fragment from a row-stride-32 swizzled tile.
__device__ __forceinline__ bf16x8 read_frag(const ushort_t* tile, int row, int quad) {
  int g = quad ^ ((row >> 1) & 3);
  return *(const bf16x8*)(tile + row * 32 + g * 8);
}

// ---------------------------------------------------------------------------
// [128 x 32] tile staging with 256 threads: thread t = (row t>>1, half t&1).
// store target can be LDS or global (convert pass writes the same image).
// ---------------------------------------------------------------------------
template <int DT> struct TR16 { float4 f[4]; bf16x8 h[2]; };

template <int DT>
__device__ __forceinline__ void t16_load(const void* gv, size_t base, int tid, TR16<DT>& t) {
  const int row = tid >> 1, half = tid & 1;
  const size_t off = base + (size_t)row * D_ + half * 16;
  if constexpr (DT == 0) {
    const float4* s = (const float4*)((const float*)gv + off);
    t.f[0] = s[0]; t.f[1] = s[1]; t.f[2] = s[2]; t.f[3] = s[3];
  } else {
    const bf16x8* s = (const bf16x8*)((const ushort_t*)gv + off);
    t.h[0] = s[0]; t.h[1] = s[1];
  }
}
template <int DT>
__device__ __forceinline__ void t16_store(ushort_t* tile, int tid, const TR16<DT>& t) {
  const int row = tid >> 1, half = tid & 1;
  bf16x8 ch0, ch1;
  if constexpr (DT == 0) {
    ushort_t u[16];
    u[0]  = f2b(t.f[0].x); u[1]  = f2b(t.f[0].y); u[2]  = f2b(t.f[0].z); u[3]  = f2b(t.f[0].w);
    u[4]  = f2b(t.f[1].x); u[5]  = f2b(t.f[1].y); u[6]  = f2b(t.f[1].z); u[7]  = f2b(t.f[1].w);
    u[8]  = f2b(t.f[2].x); u[9]  = f2b(t.f[2].y); u[10] = f2b(t.f[2].z); u[11] = f2b(t.f[2].w);
    u[12] = f2b(t.f[3].x); u[13] = f2b(t.f[3].y); u[14] = f2b(t.f[3].z); u[15] = f2b(t.f[3].w);
    ch0 = *(const bf16x8*)u; ch1 = *(const bf16x8*)(u + 8);
  } else { ch0 = t.h[0]; ch1 = t.h[1]; }
  const int swz = (row >> 1) & 3, c0 = half * 2;
  *(bf16x8*)(tile + row * 32 + (((c0    ) ^ swz) << 3)) = ch0;
  *(bf16x8*)(tile + row * 32 + (((c0 + 1) ^ swz) << 3)) = ch1;
}

// gate A tile [128 x 32] with 512 threads: thread t = (row t>>2, group t&3), 8 elems.
template <int DT> struct TRA { float4 f[2]; bf16x8 h; };

template <int DT>
__device__ __forceinline__ void ta_load(const void* gv, size_t base, int tid, TRA<DT>& t) {
  const int row = tid >> 2, g = tid & 3;
  const size_t off = base + (size_t)row * D_ + g * 8;
  if constexpr (DT == 0) {
    const float4* s = (const float4*)((const float*)gv + off);
    t.f[0] = s[0]; t.f[1] = s[1];
  } else {
    t.h = *(const bf16x8*)((const ushort_t*)gv + off);
  }
}
template <int DT>
__device__ __forceinline__ void ta_store(ushort_t* tile, int tid, const TRA<DT>& t) {
  const int row = tid >> 2, g = tid & 3;
  bf16x8 ch;
  if constexpr (DT == 0) {
    ushort_t u[8];
    u[0] = f2b(t.f[0].x); u[1] = f2b(t.f[0].y); u[2] = f2b(t.f[0].z); u[3] = f2b(t.f[0].w);
    u[4] = f2b(t.f[1].x); u[5] = f2b(t.f[1].y); u[6] = f2b(t.f[1].z); u[7] = f2b(t.f[1].w);
    ch = *(const bf16x8*)u;
  } else ch = t.h;
  const int swz = (row >> 1) & 3;
  *(bf16x8*)(tile + row * 32 + ((g ^ swz) << 3)) = ch;
}

// ---------------------------------------------------------------------------
// Weight pre-pass: convert shareW / langsW / W1 to bf16 in TILED, PRE-SWIZZLED
// layout (exact LDS tile image, 8 KB per [128x32] tile) + biases to f32.
// Removes the 512x-repeated in-kernel f2b of weights and enables
// global_load_lds direct staging (linear LDS dest, swizzle baked in source).
// ---------------------------------------------------------------------------
__global__ __launch_bounds__(256)
void convert_kernel(const void* __restrict__ shareW, const void* __restrict__ langsW,
                    const void* __restrict__ gW1, const void* __restrict__ gb1,
                    const void* __restrict__ gW2, const void* __restrict__ gb2,
                    const int* __restrict__ flag, char* __restrict__ ws) {
  const int t = blockIdx.x, tid = threadIdx.x;
  const int dt = flag[0];
  if (t < 1088) {
    const void* src; ushort_t* dst; size_t sb;
    if (t < 64) {                                         // shareW: et*16 + kt
      src = shareW; dst = (ushort_t*)(ws + WS_SW) + (size_t)t * 4096;
      sb = ((size_t)(t >> 4) * 128) * D_ + (size_t)(t & 15) * 32;
    } else if (t < 576) {                                 // langsW: (lg*4+et)*16+kt
      const int t2 = t - 64;
      src = langsW; dst = (ushort_t*)(ws + WS_LW) + (size_t)t2 * 4096;
      sb = ((size_t)(t2 >> 6) * 512 + (size_t)((t2 >> 4) & 3) * 128) * D_ + (size_t)(t2 & 15) * 32;
    } else {                                              // W1: same shape as langsW
      const int t3 = t - 576;
      src = gW1; dst = (ushort_t*)(ws + WS_W1) + (size_t)t3 * 4096;
      sb = ((size_t)(t3 >> 6) * 512 + (size_t)((t3 >> 4) & 3) * 128) * D_ + (size_t)(t3 & 15) * 32;
    }
    if (dt == 0) { TR16<0> r; t16_load<0>(src, sb, tid, r); t16_store<0>(dst, tid, r); }
    else         { TR16<1> r; t16_load<1>(src, sb, tid, r); t16_store<1>(dst, tid, r); }
  } else {                                                // biases -> f32
    float* b1f = (float*)(ws + WS_B1F);
    float* w2f = (float*)(ws + WS_W2F);
    float* b2w = (float*)(ws + WS_B2F);
    for (int i = tid; i < 4096; i += 256) {
      b1f[i] = dt ? b2f(((const ushort_t*)gb1)[i]) : ((const float*)gb1)[i];
      w2f[i] = dt ? b2f(((const ushort_t*)gW2)[i]) : ((const float*)gW2)[i];
    }
    if (tid < 8)
      b2w[tid] = dt ? b2f(((const ushort_t*)gb2)[tid]) : ((const float*)gb2)[tid];
  }
}

// ---------------------------------------------------------------------------
// Shared-memory layouts (declared once per __global__, passed into DT bodies).
// ---------------------------------------------------------------------------
struct GateSmem {
  alignas(16) ushort_t As[2][128 * 32];   // 16 KB
  alignas(16) ushort_t Bs[2][512 * 32];   // 64 KB
  float b1s[512], w2s[512], logit[128];   // 4.5 KB
};
struct OutSmem {
  alignas(16) ushort_t As[2][128 * 32];   // 16 KB
  alignas(16) ushort_t Ss[2][128 * 32];   // 16 KB
  alignas(16) ushort_t Ls[2][128 * 32];   // 16 KB
};

// ---------------------------------------------------------------------------
// Kernel 1: gate[b,s]. 128 s-rows x ALL 512 e per block (8 waves, 2x4).
// W1 staged via global_load_lds from tiled-bf16 ws (no f2b, no ds_write);
// old_x reg-staged (8 f2b/thread/step). Single barrier per k-step, dbuf LDS.
// ---------------------------------------------------------------------------
template <int DT>
__device__ __forceinline__ void gate_body(const void* __restrict__ old_x,
    const int* __restrict__ lang, const ushort_t* __restrict__ w1t,
    const float* __restrict__ b1f, const float* __restrict__ w2f,
    const float* __restrict__ b2w, float* __restrict__ gate, GateSmem& sm) {
  int bid = blockIdx.y * gridDim.x + blockIdx.x;            // 0..511
  int swz = (bid & 7) * 64 + (bid >> 3);                    // XCD-chunked
  const int s0 = (swz & 15) * 128;
  const int b  = swz >> 4;
  const int tid  = threadIdx.x;
  const int wave = tid >> 6, lane = tid & 63, quad = lane >> 4, ln = lane & 15;
  const int m_off = (wave >> 2) * 64;      // 2 wave-rows of 64 s
  const int n_off = (wave & 3) * 128;      // 4 wave-cols of 128 e
  const int lg = lang[b];

  sm.b1s[tid] = b1f[lg * 512 + tid];
  sm.w2s[tid] = w2f[lg * 512 + tid];
  if (tid < 128) sm.logit[tid] = 0.f;

  const size_t Aoff = ((size_t)b * S_ + s0) * D_;
  const ushort_t* w1base = w1t + (size_t)lg * 64 * 4096;    // 64 tiles per lang

  // stage W1 k-tile kt (512 e-rows x 32 k = 32 KB) into Bs[buf]: 32 slices of 1 KB
  auto stageB = [&](int kt, int buf) {
    #pragma unroll
    for (int c = 0; c < 4; ++c) {
      const int sl = c * 8 + wave;                          // 0..31
      const int et = sl >> 3;                               // 128-row tile index
      const char* g = (const char*)(w1base + ((size_t)(et * 16 + kt)) * 4096)
                      + (sl & 7) * 1024 + lane * 16;
      gload16(g, (char*)sm.Bs[buf] + sl * 1024);
    }
  };

  f32x4 acc[4][8];
  #pragma unroll
  for (int i = 0; i < 4; ++i)
    #pragma unroll
    for (int j = 0; j < 8; ++j) { f32x4 z = {0.f, 0.f, 0.f, 0.f}; acc[i][j] = z; }

  TRA<DT> ta;
  stageB(0, 0);
  ta_load<DT>(old_x, Aoff, tid, ta);
  ta_store<DT>(sm.As[0], tid, ta);
  __syncthreads();

  const int rrow  = tid >> 2, rg = tid & 3;
  const int rslot = (rg ^ ((rrow >> 1) & 3)) << 3;
  float res = 0.f;

  for (int step = 0; step < 16; ++step) {
    const int cur = step & 1;
    if (step < 15) {                       // prefetch next k-step
      stageB(step + 1, cur ^ 1);           // direct-to-LDS, in flight across MFMA
      ta_load<DT>(old_x, Aoff + (step + 1) * 32, tid, ta);
    }
    bf16x8 af[4];
    #pragma unroll
    for (int mf = 0; mf < 4; ++mf)
      af[mf] = read_frag(sm.As[cur], m_off + mf * 16 + ln, quad);
    {   // residual partial: sum_k old_x[s,k] * w2[k] from staged tile
      bf16x8 rv = *(const bf16x8*)(sm.As[cur] + rrow * 32 + rslot);
      #pragma unroll
      for (int j = 0; j < 8; ++j)
        res += b2f((ushort_t)rv[j]) * sm.w2s[step * 32 + rg * 8 + j];
    }
    #pragma unroll
    for (int nh = 0; nh < 2; ++nh) {       // split B frags to cap live regs
      bf16x8 bfr[4];
      #pragma unroll
      for (int nf = 0; nf < 4; ++nf)
        bfr[nf] = read_frag(sm.Bs[cur], n_off + (nh * 4 + nf) * 16 + ln, quad);
      #pragma unroll
      for (int mf = 0; mf < 4; ++mf)
        #pragma unroll
        for (int nf = 0; nf < 4; ++nf)
          acc[mf][nh * 4 + nf] = mfma16(af[mf], bfr[nf], acc[mf][nh * 4 + nf]);
    }
    if (step < 15) ta_store<DT>(sm.As[cur ^ 1], tid, ta);
    __syncthreads();                       // ONE barrier per k-step
  }
  atomicAdd(&sm.logit[rrow], res);

  float logacc[16];
  #pragma unroll
  for (int i = 0; i < 16; ++i) logacc[i] = 0.f;
  #pragma unroll
  for (int nf = 0; nf < 8; ++nf) {
    int e = n_off + nf * 16 + ln;
    float b1v = sm.b1s[e], w2v = sm.w2s[e];
    #pragma unroll
    for (int mf = 0; mf < 4; ++mf)
      #pragma unroll
      for (int r = 0; r < 4; ++r) {
        float v = acc[mf][nf][r] + b1v;
        logacc[mf * 4 + r] += fmaxf(v, 0.f) * w2v;
      }
  }
  #pragma unroll
  for (int off = 1; off < 16; off <<= 1)
    #pragma unroll
    for (int i = 0; i < 16; ++i)
      logacc[i] += __shfl_xor(logacc[i], off, 64);
  if (ln == 0) {
    #pragma unroll
    for (int mf = 0; mf < 4; ++mf)
      #pragma unroll
      for (int r = 0; r < 4; ++r)
        atomicAdd(&sm.logit[m_off + mf * 16 + quad * 4 + r], logacc[mf * 4 + r]);
  }
  __syncthreads();
  if (tid < 128) {
    float l = sm.logit[tid] + b2w[lg];
    gate[(size_t)b * S_ + s0 + tid] = 1.f / (1.f + expf(-l));
  }
}

__global__ __launch_bounds__(512, 2)
void gate_kernel(const void* __restrict__ old_x, const int* __restrict__ lang,
                 const ushort_t* __restrict__ w1t, const float* __restrict__ b1f,
                 const float* __restrict__ w2f, const float* __restrict__ b2w,
                 const int* __restrict__ flag, float* __restrict__ gate) {
  __shared__ GateSmem sm;                  // single 84.5 KB instance
  if (flag[0] == 0) gate_body<0>(old_x, lang, w1t, b1f, w2f, b2w, gate, sm);
  else              gate_body<1>(old_x, lang, w1t, b1f, w2f, b2w, gate, sm);
}

// ---------------------------------------------------------------------------
// Kernel 2: out = (1-g)*x@share_W^T + g*x@langs_W[lang]^T
// S/L weight tiles via global_load_lds from tiled-bf16 ws; x reg-staged.
// ---------------------------------------------------------------------------
template <int DT>
__device__ __forceinline__ void out_body(const void* __restrict__ x,
    const int* __restrict__ lang, const ushort_t* __restrict__ sWt,
    const ushort_t* __restrict__ lWt, const float* __restrict__ gate,
    void* __restrict__ out, OutSmem& sm) {
  int bid = (blockIdx.z * gridDim.y + blockIdx.y) * gridDim.x + blockIdx.x;  // 0..2047
  int swz = (bid & 7) * 256 + (bid >> 3);                  // XCD-chunked
  const int eb = swz & 3, e0 = eb * 128;
  const int s0 = ((swz >> 2) & 15) * 128;
  const int b  = swz >> 6;
  const int tid  = threadIdx.x;
  const int wave = tid >> 6, lane = tid & 63, quad = lane >> 4, ln = lane & 15;
  const int m_off = (wave >> 1) * 64, n_off = (wave & 1) * 64;
  const int lg = lang[b];

  const size_t Aoff = ((size_t)b * S_ + s0) * D_;
  const ushort_t* Sbase = sWt + (size_t)eb * 16 * 4096;
  const ushort_t* Lbase = lWt + ((size_t)(lg * 4 + eb)) * 16 * 4096;

  // stage S+L k-tile kt (8 KB each) via gload_lds: 8 slices of 1 KB per tile
  auto stageSL = [&](int kt, int buf) {
    #pragma unroll
    for (int c = 0; c < 2; ++c) {
      const int sl = c * 4 + wave;                          // 0..7
      const int boff = sl * 1024 + lane * 16;
      gload16((const char*)(Sbase + (size_t)kt * 4096) + boff,
              (char*)sm.Ss[buf] + sl * 1024);
      gload16((const char*)(Lbase + (size_t)kt * 4096) + boff,
              (char*)sm.Ls[buf] + sl * 1024);
    }
  };

  f32x4 accS[4][4], accL[4][4];
  #pragma unroll
  for (int i = 0; i < 4; ++i)
    #pragma unroll
    for (int j = 0; j < 4; ++j) {
      f32x4 z = {0.f, 0.f, 0.f, 0.f};
      accS[i][j] = z; accL[i][j] = z;
    }

  TR16<DT> ta;
  stageSL(0, 0);
  t16_load<DT>(x, Aoff, tid, ta);
  t16_store<DT>(sm.As[0], tid, ta);
  __syncthreads();

  for (int step = 0; step < 16; ++step) {
    const int cur = step & 1;
    if (step < 15) {
      stageSL(step + 1, cur ^ 1);
      t16_load<DT>(x, Aoff + (step + 1) * 32, tid, ta);
    }
    bf16x8 af[4], sf[4], lf[4];
    #pragma unroll
    for (int mf = 0; mf < 4; ++mf)
      af[mf] = read_frag(sm.As[cur], m_off + mf * 16 + ln, quad);
    #pragma unroll
    for (int nf = 0; nf < 4; ++nf) {
      sf[nf] = read_frag(sm.Ss[cur], n_off + nf * 16 + ln, quad);
      lf[nf] = read_frag(sm.Ls[cur], n_off + nf * 16 + ln, quad);
    }
    #pragma unroll
    for (int mf = 0; mf < 4; ++mf)
      #pragma unroll
      for (int nf = 0; nf < 4; ++nf) {
        accS[mf][nf] = mfma16(af[mf], sf[nf], accS[mf][nf]);
        accL[mf][nf] = mfma16(af[mf], lf[nf], accL[mf][nf]);
      }
    if (step < 15) t16_store<DT>(sm.As[cur ^ 1], tid, ta);
    __syncthreads();
  }

  // epilogue: blend with gate, plain stores (nt stores caused +35% WRITE_SIZE:
  // 4B-scattered lanes need L2 write-coalescing).
  #pragma unroll
  for (int mf = 0; mf < 4; ++mf) {
    int srow = s0 + m_off + mf * 16 + quad * 4;
    float gv[4];
    #pragma unroll
    for (int r = 0; r < 4; ++r) gv[r] = gate[(size_t)b * S_ + srow + r];
    #pragma unroll
    for (int nf = 0; nf < 4; ++nf) {
      int col = e0 + n_off + nf * 16 + ln;
      f32x4 cs = accS[mf][nf], cl = accL[mf][nf];
      #pragma unroll
      for (int r = 0; r < 4; ++r) {
        float v = cs[r] + gv[r] * (cl[r] - cs[r]);
        size_t idx = ((size_t)b * S_ + srow + r) * D_ + col;
        if constexpr (DT == 0) ((float*)out)[idx] = v;
        else                   ((ushort_t*)out)[idx] = f2b(v);
      }
    }
  }
}

__global__ __launch_bounds__(256, 2)
void out_kernel(const void* __restrict__ x, const int* __restrict__ lang,
                const ushort_t* __restrict__ sWt, const ushort_t* __restrict__ lWt,
                const float* __restrict__ gate, const int* __restrict__ flag,
                void* __restrict__ out) {
  __shared__ OutSmem sm;                   // single 48 KB instance
  if (flag[0] == 0) out_body<0>(x, lang, sWt, lWt, gate, out, sm);
  else              out_body<1>(x, lang, sWt, lWt, gate, out, sm);
}

extern "C" void kernel_launch(void* const* d_in, const int* in_sizes, int n_in,
                              void* d_out, int out_size, void* d_ws, size_t ws_size,
                              hipStream_t stream) {
  const void* old_x  = d_in[0];
  const void* x      = d_in[1];
  const int*  lang   = (const int*)d_in[2];
  const void* shareW = d_in[3];
  const void* langsW = d_in[4];
  const void* gW1    = d_in[5];
  const void* gb1    = d_in[6];
  const void* gW2    = d_in[7];
  const void* gb2    = d_in[8];

  char*  ws   = (char*)d_ws;
  float* gate = (float*)(ws + WS_GATE);
  int*   flag = (int*)(ws + WS_FLAG);
  const ushort_t* sWt = (const ushort_t*)(ws + WS_SW);
  const ushort_t* lWt = (const ushort_t*)(ws + WS_LW);
  const ushort_t* w1t = (const ushort_t*)(ws + WS_W1);
  const float*    b1f = (const float*)(ws + WS_B1F);
  const float*    w2f = (const float*)(ws + WS_W2F);
  const float*    b2w = (const float*)(ws + WS_B2F);

  detect_kernel<<<1, 256, 0, stream>>>((const unsigned int*)old_x, flag);

  convert_kernel<<<1089, 256, 0, stream>>>(shareW, langsW, gW1, gb1, gW2, gb2,
                                           flag, ws);

  dim3 g1(S_ / 128, B_);
  gate_kernel<<<g1, dim3(512), 0, stream>>>(old_x, lang, w1t, b1f, w2f, b2w,
                                            flag, gate);

  dim3 g2(D_ / 128, S_ / 128, B_);
  out_kernel<<<g2, dim3(256), 0, stream>>>(x, lang, sWt, lWt, gate, flag, d_out);
}